// Round 2
// baseline (2264.002 us; speedup 1.0000x reference)
//
#include <hip/hip_runtime.h>

#define N_NODES 50000
#define N_EDGES 800000
#define DIM 64
#define NUM_GRAPHS 64

// ---- degree count (atomic int histogram over dst) ----
__global__ void count_deg_kernel(const int* __restrict__ dst, int* __restrict__ cnt, int E) {
  int e = blockIdx.x * blockDim.x + threadIdx.x;
  if (e < E) atomicAdd(&cnt[dst[e]], 1);
}

__global__ void make_dis_kernel(const int* __restrict__ cnt, float* __restrict__ dis, int N) {
  int i = blockIdx.x * blockDim.x + threadIdx.x;
  if (i < N) dis[i] = 1.0f / sqrtf((float)(cnt[i] + 1));
}

// ---- skinny GEMM: H[N,64] = X[N,64] @ W[64,64], W+4 X rows staged in LDS ----
__global__ void gemm_kernel(const float* __restrict__ X, const float* __restrict__ W,
                            float* __restrict__ H, int N) {
  __shared__ float Ws[DIM][DIM];
  __shared__ float Xs[4][DIM];
  for (int i = threadIdx.x; i < DIM * DIM; i += 256) Ws[i >> 6][i & 63] = W[i];
  int row0 = blockIdx.x * 4;
  {
    int idx = threadIdx.x;           // 0..255
    int r = row0 + (idx >> 6);
    Xs[idx >> 6][idx & 63] = (r < N) ? X[(size_t)r * DIM + (idx & 63)] : 0.f;
  }
  __syncthreads();
  int col = threadIdx.x & 63;        // lane within wave
  int rq  = threadIdx.x >> 6;        // wave index in block
  int row = row0 + rq;
  if (row < N) {
    float acc = 0.f;
    #pragma unroll
    for (int k = 0; k < DIM; ++k) acc = fmaf(Xs[rq][k], Ws[k][col], acc);
    H[(size_t)row * DIM + col] = acc;
  }
}

// ---- edge scatter: 16 threads/edge, float4 gather + 4 scalar atomicAdds ----
__global__ void scatter_kernel(const int* __restrict__ src, const int* __restrict__ dst,
                               const float* __restrict__ dis, const float* __restrict__ H,
                               float* __restrict__ A, int E) {
  int t = blockIdx.x * blockDim.x + threadIdx.x;
  int e = t >> 4;
  if (e >= E) return;
  int part = t & 15;
  int s = src[e], d = dst[e];
  float norm = dis[s] * dis[d];
  const float4 v = *reinterpret_cast<const float4*>(H + (size_t)s * DIM + part * 4);
  float* outp = A + (size_t)d * DIM + part * 4;
  atomicAdd(outp + 0, v.x * norm);
  atomicAdd(outp + 1, v.y * norm);
  atomicAdd(outp + 2, v.z * norm);
  atomicAdd(outp + 3, v.w * norm);
}

// ---- finalize: A = relu(A + H*dis^2 + b) in place ----
__global__ void finalize_kernel(float* __restrict__ A, const float* __restrict__ H,
                                const float* __restrict__ dis, const float* __restrict__ b, int N) {
  int i = blockIdx.x * blockDim.x + threadIdx.x;
  if (i >= N * DIM) return;
  int node = i >> 6, col = i & 63;
  float ds = dis[node];
  float v = A[i] + H[i] * (ds * ds) + b[col];
  A[i] = fmaxf(v, 0.f);
}

// ---- fused mean-pool (sorted batch, binary-search ranges) + final linear ----
__global__ void pool_kernel(const float* __restrict__ F, const int* __restrict__ batch,
                            const float* __restrict__ Wl, const float* __restrict__ bl,
                            float* __restrict__ out, int N) {
  int g = blockIdx.x;
  // lower_bound(g), lower_bound(g+1)
  int lo = 0, hi = N;
  while (lo < hi) { int mid = (lo + hi) >> 1; if (batch[mid] < g) lo = mid + 1; else hi = mid; }
  int start = lo;
  hi = N;  // lo already >= start
  while (lo < hi) { int mid = (lo + hi) >> 1; if (batch[mid] < g + 1) lo = mid + 1; else hi = mid; }
  int end = lo;

  int col = threadIdx.x & 63;
  int q   = threadIdx.x >> 6;
  float acc = 0.f;
  for (int n = start + q; n < end; n += 4) acc += F[(size_t)n * DIM + col];

  __shared__ float sums[4][DIM];
  sums[q][col] = acc;
  __syncthreads();
  if (q == 0) {
    float s = sums[0][col] + sums[1][col] + sums[2][col] + sums[3][col];
    float cntf = fmaxf((float)(end - start), 1.f);
    float val = (s / cntf) * Wl[col];
    #pragma unroll
    for (int off = 32; off > 0; off >>= 1) val += __shfl_down(val, off, 64);
    if (col == 0) out[g] = val + bl[0];
  }
}

extern "C" void kernel_launch(void* const* d_in, const int* in_sizes, int n_in,
                              void* d_out, int out_size, void* d_ws, size_t ws_size,
                              hipStream_t stream) {
  const float* x     = (const float*)d_in[0];
  const int*   ei    = (const int*)d_in[1];   // int64 in reference, delivered as int32
  const int*   batch = (const int*)d_in[2];
  const float* W1 = (const float*)d_in[3];
  const float* b1 = (const float*)d_in[4];
  const float* W2 = (const float*)d_in[5];
  const float* b2 = (const float*)d_in[6];
  const float* W3 = (const float*)d_in[7];
  const float* b3 = (const float*)d_in[8];
  const float* Wl = (const float*)d_in[9];
  const float* bl = (const float*)d_in[10];
  float* out = (float*)d_out;

  const int* srcp = ei;
  const int* dstp = ei + N_EDGES;

  char* ws = (char*)d_ws;
  size_t off = 0;
  auto alloc = [&](size_t bytes) { void* p = ws + off; off += (bytes + 255) & ~(size_t)255; return p; };
  int*   cnt  = (int*)  alloc((size_t)N_NODES * 4);
  float* dis  = (float*)alloc((size_t)N_NODES * 4);
  float* bufA = (float*)alloc((size_t)N_NODES * DIM * 4);
  float* bufB = (float*)alloc((size_t)N_NODES * DIM * 4);

  hipMemsetAsync(cnt, 0, (size_t)N_NODES * 4, stream);
  count_deg_kernel<<<(N_EDGES + 255) / 256, 256, 0, stream>>>(dstp, cnt, N_EDGES);
  make_dis_kernel<<<(N_NODES + 255) / 256, 256, 0, stream>>>(cnt, dis, N_NODES);

  const float* Wm[3] = {W1, W2, W3};
  const float* bm[3] = {b1, b2, b3};
  const float* F = x;
  for (int l = 0; l < 3; ++l) {
    gemm_kernel<<<(N_NODES + 3) / 4, 256, 0, stream>>>(F, Wm[l], bufA, N_NODES);
    hipMemsetAsync(bufB, 0, (size_t)N_NODES * DIM * 4, stream);
    scatter_kernel<<<(int)(((size_t)N_EDGES * 16 + 255) / 256), 256, 0, stream>>>(
        srcp, dstp, dis, bufA, bufB, N_EDGES);
    finalize_kernel<<<(N_NODES * DIM + 255) / 256, 256, 0, stream>>>(bufB, bufA, dis, bm[l], N_NODES);
    F = bufB;
  }
  pool_kernel<<<NUM_GRAPHS, 256, 0, stream>>>(bufB, batch, Wl, bl, out, N_NODES);
}

// Round 3
// 347.538 us; speedup vs baseline: 6.5144x; 6.5144x over previous
//
#include <hip/hip_runtime.h>

#define N_NODES 50000
#define N_EDGES 800000
#define DIM 64
#define NUM_GRAPHS 64

// ---- degree count (atomic int histogram over dst) ----
__global__ void count_deg_kernel(const int* __restrict__ dst, int* __restrict__ cnt, int E) {
  int e = blockIdx.x * blockDim.x + threadIdx.x;
  if (e < E) atomicAdd(&cnt[dst[e]], 1);
}

__global__ void make_dis_kernel(const int* __restrict__ cnt, float* __restrict__ dis, int N) {
  int i = blockIdx.x * blockDim.x + threadIdx.x;
  if (i < N) dis[i] = 1.0f / sqrtf((float)(cnt[i] + 1));
}

// ---- exclusive scan of cnt -> rowptr[N+1], single block of 1024 threads ----
__global__ void scan_kernel(const int* __restrict__ cnt, int* __restrict__ rowptr, int N) {
  __shared__ int wsum[16];
  __shared__ int chunk_total;
  __shared__ int running_s;
  int lane = threadIdx.x & 63, wid = threadIdx.x >> 6;
  if (threadIdx.x == 0) running_s = 0;
  __syncthreads();
  for (int base = 0; base < N; base += 1024) {
    int i = base + threadIdx.x;
    int v = (i < N) ? cnt[i] : 0;
    int sv = v;
    #pragma unroll
    for (int off = 1; off < 64; off <<= 1) {
      int t = __shfl_up(sv, off, 64);
      if (lane >= off) sv += t;
    }
    if (lane == 63) wsum[wid] = sv;
    __syncthreads();
    if (wid == 0) {
      int wv = (lane < 16) ? wsum[lane] : 0;
      #pragma unroll
      for (int off = 1; off < 16; off <<= 1) {
        int t = __shfl_up(wv, off, 64);
        if (lane >= off) wv += t;
      }
      if (lane < 16) wsum[lane] = wv;
      if (lane == 15) chunk_total = wv;
    }
    __syncthreads();
    int wexcl = (wid == 0) ? 0 : wsum[wid - 1];
    if (i < N) rowptr[i] = running_s + wexcl + (sv - v);
    __syncthreads();
    if (threadIdx.x == 0) running_s += chunk_total;
    __syncthreads();
  }
  if (threadIdx.x == 0) rowptr[N] = running_s;
}

// ---- fill CSR: esrc[pos] = src of each edge, bucketed by dst ----
__global__ void fill_kernel(const int* __restrict__ src, const int* __restrict__ dst,
                            int* __restrict__ cursor, int* __restrict__ esrc, int E) {
  int e = blockIdx.x * blockDim.x + threadIdx.x;
  if (e < E) {
    int d = dst[e];
    int p = atomicAdd(&cursor[d], 1);
    esrc[p] = src[e];
  }
}

// ---- aggregate: A_i = dis_i * ( sum_{j in in(i)} dis_j * F_j  +  dis_i * F_i ) ----
// one wave per node; lane = feature column
__global__ __launch_bounds__(256) void aggregate_kernel(const float* __restrict__ F,
    const int* __restrict__ rowptr, const int* __restrict__ esrc,
    const float* __restrict__ dis, float* __restrict__ A, int N) {
  int node = blockIdx.x * 4 + (threadIdx.x >> 6);
  if (node >= N) return;
  int lane = threadIdx.x & 63;
  int beg = rowptr[node], end = rowptr[node + 1];
  float acc0 = 0.f, acc1 = 0.f, acc2 = 0.f, acc3 = 0.f;
  int j = beg;
  for (; j + 4 <= end; j += 4) {
    int s0 = esrc[j], s1 = esrc[j + 1], s2 = esrc[j + 2], s3 = esrc[j + 3];
    float d0 = dis[s0], d1 = dis[s1], d2 = dis[s2], d3 = dis[s3];
    acc0 += F[(size_t)s0 * DIM + lane] * d0;
    acc1 += F[(size_t)s1 * DIM + lane] * d1;
    acc2 += F[(size_t)s2 * DIM + lane] * d2;
    acc3 += F[(size_t)s3 * DIM + lane] * d3;
  }
  for (; j < end; ++j) {
    int s = esrc[j];
    acc0 += F[(size_t)s * DIM + lane] * dis[s];
  }
  float dn = dis[node];
  float self = F[(size_t)node * DIM + lane] * dn;
  A[(size_t)node * DIM + lane] = (acc0 + acc1 + acc2 + acc3 + self) * dn;
}

// ---- fused GEMM + bias + relu: F = relu(A @ W + b) ----
// W[k][col] held in 64 VGPRs per lane; X rows broadcast from LDS as float4
__global__ __launch_bounds__(256) void gemm_bias_relu(const float* __restrict__ X,
    const float* __restrict__ W, const float* __restrict__ b,
    float* __restrict__ F, int N) {
  __shared__ float4 Xs[16][16];  // 16 rows x 64 floats
  int col = threadIdx.x & 63, wid = threadIdx.x >> 6;
  float wreg[DIM];
  #pragma unroll
  for (int k = 0; k < DIM; ++k) wreg[k] = W[k * DIM + col];
  float bias = b[col];
  int row0 = blockIdx.x * 16;
  {
    int i = threadIdx.x;           // 256 threads -> 16 rows x 16 float4
    int r = i >> 4, c = i & 15;
    int gr = row0 + r;
    Xs[r][c] = (gr < N) ? reinterpret_cast<const float4*>(X)[(size_t)gr * 16 + c]
                        : make_float4(0.f, 0.f, 0.f, 0.f);
  }
  __syncthreads();
  #pragma unroll
  for (int rr = 0; rr < 4; ++rr) {
    int lr = wid * 4 + rr;
    int row = row0 + lr;
    if (row >= N) continue;
    float a0 = 0.f, a1 = 0.f, a2 = 0.f, a3 = 0.f;
    #pragma unroll
    for (int kk = 0; kk < 16; ++kk) {
      float4 xv = Xs[lr][kk];
      a0 = fmaf(xv.x, wreg[4 * kk + 0], a0);
      a1 = fmaf(xv.y, wreg[4 * kk + 1], a1);
      a2 = fmaf(xv.z, wreg[4 * kk + 2], a2);
      a3 = fmaf(xv.w, wreg[4 * kk + 3], a3);
    }
    float v = a0 + a1 + a2 + a3 + bias;
    F[(size_t)row * DIM + col] = fmaxf(v, 0.f);
  }
}

// ---- fused mean-pool (sorted batch, binary-search ranges) + final linear ----
__global__ void pool_kernel(const float* __restrict__ F, const int* __restrict__ batch,
                            const float* __restrict__ Wl, const float* __restrict__ bl,
                            float* __restrict__ out, int N) {
  int g = blockIdx.x;
  int lo = 0, hi = N;
  while (lo < hi) { int mid = (lo + hi) >> 1; if (batch[mid] < g) lo = mid + 1; else hi = mid; }
  int start = lo;
  hi = N;
  while (lo < hi) { int mid = (lo + hi) >> 1; if (batch[mid] < g + 1) lo = mid + 1; else hi = mid; }
  int end = lo;

  int col = threadIdx.x & 63;
  int q   = threadIdx.x >> 6;
  float acc = 0.f;
  for (int n = start + q; n < end; n += 4) acc += F[(size_t)n * DIM + col];

  __shared__ float sums[4][DIM];
  sums[q][col] = acc;
  __syncthreads();
  if (q == 0) {
    float s = sums[0][col] + sums[1][col] + sums[2][col] + sums[3][col];
    float cntf = fmaxf((float)(end - start), 1.f);
    float val = (s / cntf) * Wl[col];
    #pragma unroll
    for (int off = 32; off > 0; off >>= 1) val += __shfl_down(val, off, 64);
    if (col == 0) out[g] = val + bl[0];
  }
}

extern "C" void kernel_launch(void* const* d_in, const int* in_sizes, int n_in,
                              void* d_out, int out_size, void* d_ws, size_t ws_size,
                              hipStream_t stream) {
  const float* x     = (const float*)d_in[0];
  const int*   ei    = (const int*)d_in[1];   // int64 in reference, delivered as int32
  const int*   batch = (const int*)d_in[2];
  const float* W1 = (const float*)d_in[3];
  const float* b1 = (const float*)d_in[4];
  const float* W2 = (const float*)d_in[5];
  const float* b2 = (const float*)d_in[6];
  const float* W3 = (const float*)d_in[7];
  const float* b3 = (const float*)d_in[8];
  const float* Wl = (const float*)d_in[9];
  const float* bl = (const float*)d_in[10];
  float* out = (float*)d_out;

  const int* srcp = ei;
  const int* dstp = ei + N_EDGES;

  char* ws = (char*)d_ws;
  size_t off = 0;
  auto alloc = [&](size_t bytes) { void* p = ws + off; off += (bytes + 255) & ~(size_t)255; return p; };
  int*   cnt    = (int*)  alloc((size_t)N_NODES * 4);       // later reused as cursor
  float* dis    = (float*)alloc((size_t)N_NODES * 4);
  int*   rowptr = (int*)  alloc((size_t)(N_NODES + 1) * 4);
  int*   esrc   = (int*)  alloc((size_t)N_EDGES * 4);
  float* bufA   = (float*)alloc((size_t)N_NODES * DIM * 4); // aggregate output
  float* bufB   = (float*)alloc((size_t)N_NODES * DIM * 4); // layer output

  // ---- CSR build ----
  hipMemsetAsync(cnt, 0, (size_t)N_NODES * 4, stream);
  count_deg_kernel<<<(N_EDGES + 255) / 256, 256, 0, stream>>>(dstp, cnt, N_EDGES);
  make_dis_kernel<<<(N_NODES + 255) / 256, 256, 0, stream>>>(cnt, dis, N_NODES);
  scan_kernel<<<1, 1024, 0, stream>>>(cnt, rowptr, N_NODES);
  hipMemcpyAsync(cnt, rowptr, (size_t)N_NODES * 4, hipMemcpyDeviceToDevice, stream); // cursor = rowptr
  fill_kernel<<<(N_EDGES + 255) / 256, 256, 0, stream>>>(srcp, dstp, cnt, esrc, N_EDGES);

  // ---- 3 GCN layers: aggregate raw features, then GEMM+bias+relu ----
  const float* Wm[3] = {W1, W2, W3};
  const float* bm[3] = {b1, b2, b3};
  const float* F = x;
  for (int l = 0; l < 3; ++l) {
    aggregate_kernel<<<(N_NODES + 3) / 4, 256, 0, stream>>>(F, rowptr, esrc, dis, bufA, N_NODES);
    gemm_bias_relu<<<N_NODES / 16, 256, 0, stream>>>(bufA, Wm[l], bm[l], bufB, N_NODES);
    F = bufB;
  }
  pool_kernel<<<NUM_GRAPHS, 256, 0, stream>>>(bufB, batch, Wl, bl, out, N_NODES);
}

// Round 4
// 260.883 us; speedup vs baseline: 8.6782x; 1.3322x over previous
//
#include <hip/hip_runtime.h>

#define N_NODES 50000
#define N_EDGES 800000
#define DIM 64
#define NUM_GRAPHS 64

// ---- degree count (atomic int histogram over dst) ----
__global__ void count_deg_kernel(const int* __restrict__ dst, int* __restrict__ cnt, int E) {
  int e = blockIdx.x * blockDim.x + threadIdx.x;
  if (e < E) atomicAdd(&cnt[dst[e]], 1);
}

// ---- scan phase A: block-local exclusive scan of cnt, block sums, fused dis ----
__global__ void scanA_kernel(const int* __restrict__ cnt, int* __restrict__ rowptr,
                             int* __restrict__ bsum, float* __restrict__ dis, int N) {
  __shared__ int wsum[16];
  int i = blockIdx.x * 1024 + threadIdx.x;
  int lane = threadIdx.x & 63, wid = threadIdx.x >> 6;
  int v = (i < N) ? cnt[i] : 0;
  if (i < N) dis[i] = rsqrtf((float)(v + 1));
  int sv = v;
  #pragma unroll
  for (int off = 1; off < 64; off <<= 1) {
    int t = __shfl_up(sv, off, 64);
    if (lane >= off) sv += t;
  }
  if (lane == 63) wsum[wid] = sv;
  __syncthreads();
  if (wid == 0) {
    int wv = (lane < 16) ? wsum[lane] : 0;
    #pragma unroll
    for (int off = 1; off < 16; off <<= 1) {
      int t = __shfl_up(wv, off, 64);
      if (lane >= off) wv += t;
    }
    if (lane < 16) wsum[lane] = wv;
  }
  __syncthreads();
  if (i < N) rowptr[i] = (wid ? wsum[wid - 1] : 0) + (sv - v);
  if (threadIdx.x == 1023) bsum[blockIdx.x] = wsum[15];
}

// ---- scan phase B: scan the (<=64) block sums; set rowptr[N] ----
__global__ void scanB_kernel(int* __restrict__ bsum, int* __restrict__ rowptr, int nb, int N) {
  int t = threadIdx.x;
  int v = (t < nb) ? bsum[t] : 0;
  #pragma unroll
  for (int off = 1; off < 64; off <<= 1) {
    int u = __shfl_up(v, off, 64);
    if (t >= off) v += u;
  }
  if (t < nb) bsum[t] = v;
  if (t == nb - 1) rowptr[N] = v;
}

// ---- scan phase C: add block offsets; also write cursor copy ----
__global__ void scanC_kernel(int* __restrict__ rowptr, const int* __restrict__ bsum,
                             int* __restrict__ cursor, int N) {
  int b = blockIdx.x;
  int i = b * 1024 + threadIdx.x;
  if (i < N) {
    int off = b ? bsum[b - 1] : 0;
    int r = rowptr[i] + off;
    rowptr[i] = r;
    cursor[i] = r;
  }
}

// ---- fill CSR: esrc[pos] = src of each edge, bucketed by dst ----
__global__ void fill_kernel(const int* __restrict__ src, const int* __restrict__ dst,
                            int* __restrict__ cursor, int* __restrict__ esrc, int E) {
  int e = blockIdx.x * blockDim.x + threadIdx.x;
  if (e < E) {
    int d = dst[e];
    int p = atomicAdd(&cursor[d], 1);
    esrc[p] = src[e];
  }
}

// ---- aggregate: A_i = dis_i * ( sum_{j in in(i)} dis_j * F_j  +  dis_i * F_i ) ----
// one wave per node; 16-lane float4 groups, 4 edges/slot, 8 edges in flight
__global__ __launch_bounds__(256) void aggregate_kernel(const float* __restrict__ F,
    const int* __restrict__ rowptr, const int* __restrict__ esrc,
    const float* __restrict__ dis, float* __restrict__ A, int N) {
  int node = blockIdx.x * 4 + (threadIdx.x >> 6);
  if (node >= N) return;
  int lane = threadIdx.x & 63;
  int qc = lane & 15;   // float4 column index within row
  int qe = lane >> 4;   // edge slot 0..3
  const float4* __restrict__ F4 = reinterpret_cast<const float4*>(F);
  int beg = rowptr[node], end = rowptr[node + 1];
  float ax = 0.f, ay = 0.f, az = 0.f, aw = 0.f;
  int j = beg;
  for (; j + 8 <= end; j += 8) {
    int s0 = esrc[j + qe], s1 = esrc[j + 4 + qe];
    float d0 = dis[s0], d1 = dis[s1];
    float4 v0 = F4[(size_t)s0 * 16 + qc];
    float4 v1 = F4[(size_t)s1 * 16 + qc];
    ax = fmaf(v0.x, d0, ax); ay = fmaf(v0.y, d0, ay);
    az = fmaf(v0.z, d0, az); aw = fmaf(v0.w, d0, aw);
    ax = fmaf(v1.x, d1, ax); ay = fmaf(v1.y, d1, ay);
    az = fmaf(v1.z, d1, az); aw = fmaf(v1.w, d1, aw);
  }
  if (j + 4 <= end) {
    int s0 = esrc[j + qe];
    float d0 = dis[s0];
    float4 v0 = F4[(size_t)s0 * 16 + qc];
    ax = fmaf(v0.x, d0, ax); ay = fmaf(v0.y, d0, ay);
    az = fmaf(v0.z, d0, az); aw = fmaf(v0.w, d0, aw);
    j += 4;
  }
  if (j + qe < end) {
    int s = esrc[j + qe];
    float d = dis[s];
    float4 v = F4[(size_t)s * 16 + qc];
    ax = fmaf(v.x, d, ax); ay = fmaf(v.y, d, ay);
    az = fmaf(v.z, d, az); aw = fmaf(v.w, d, aw);
  }
  // reduce the 4 edge-slot groups (lanes differ in bits 4..5)
  ax += __shfl_xor(ax, 16, 64); ax += __shfl_xor(ax, 32, 64);
  ay += __shfl_xor(ay, 16, 64); ay += __shfl_xor(ay, 32, 64);
  az += __shfl_xor(az, 16, 64); az += __shfl_xor(az, 32, 64);
  aw += __shfl_xor(aw, 16, 64); aw += __shfl_xor(aw, 32, 64);
  if (qe == 0) {
    float dn = dis[node];
    float4 sf = F4[(size_t)node * 16 + qc];
    float4 r;
    r.x = (ax + sf.x * dn) * dn;
    r.y = (ay + sf.y * dn) * dn;
    r.z = (az + sf.z * dn) * dn;
    r.w = (aw + sf.w * dn) * dn;
    reinterpret_cast<float4*>(A)[(size_t)node * 16 + qc] = r;
  }
}

// ---- fused GEMM + bias + relu: F = relu(A @ W + b); 64 rows/block ----
__global__ __launch_bounds__(256) void gemm_bias_relu(const float* __restrict__ X,
    const float* __restrict__ W, const float* __restrict__ b,
    float* __restrict__ F, int N) {
  __shared__ float4 Xs[64][16];
  int col = threadIdx.x & 63, wid = threadIdx.x >> 6;
  float wreg[DIM];
  #pragma unroll
  for (int k = 0; k < DIM; ++k) wreg[k] = W[k * DIM + col];
  float bias = b[col];
  int row0 = blockIdx.x * 64;
  for (int i = threadIdx.x; i < 64 * 16; i += 256) {
    int r = i >> 4, c = i & 15;
    int gr = row0 + r;
    Xs[r][c] = (gr < N) ? reinterpret_cast<const float4*>(X)[(size_t)gr * 16 + c]
                        : make_float4(0.f, 0.f, 0.f, 0.f);
  }
  __syncthreads();
  for (int rr = 0; rr < 16; ++rr) {
    int lr = wid * 16 + rr;
    int row = row0 + lr;
    if (row >= N) break;   // uniform per wave
    float a0 = 0.f, a1 = 0.f, a2 = 0.f, a3 = 0.f;
    #pragma unroll
    for (int kk = 0; kk < 16; ++kk) {
      float4 xv = Xs[lr][kk];
      a0 = fmaf(xv.x, wreg[4 * kk + 0], a0);
      a1 = fmaf(xv.y, wreg[4 * kk + 1], a1);
      a2 = fmaf(xv.z, wreg[4 * kk + 2], a2);
      a3 = fmaf(xv.w, wreg[4 * kk + 3], a3);
    }
    float v = a0 + a1 + a2 + a3 + bias;
    F[(size_t)row * DIM + col] = fmaxf(v, 0.f);
  }
}

// ---- layer-3 fused: y = relu(A@W3+b3) . Wl, block-level graph partials ----
__global__ __launch_bounds__(256) void gemm_dot_kernel(const float* __restrict__ X,
    const float* __restrict__ W, const float* __restrict__ b, const float* __restrict__ Wl,
    const int* __restrict__ batch, float* __restrict__ partial, int N) {
  __shared__ float4 Xs[64][16];
  __shared__ float yv[64];
  __shared__ float gpart[NUM_GRAPHS];
  int col = threadIdx.x & 63, wid = threadIdx.x >> 6;
  float wreg[DIM];
  #pragma unroll
  for (int k = 0; k < DIM; ++k) wreg[k] = W[k * DIM + col];
  float bias = b[col];
  float wl = Wl[col];
  int row0 = blockIdx.x * 64;
  if (threadIdx.x < 64) { yv[threadIdx.x] = 0.f; gpart[threadIdx.x] = 0.f; }
  for (int i = threadIdx.x; i < 64 * 16; i += 256) {
    int r = i >> 4, c = i & 15;
    int gr = row0 + r;
    Xs[r][c] = (gr < N) ? reinterpret_cast<const float4*>(X)[(size_t)gr * 16 + c]
                        : make_float4(0.f, 0.f, 0.f, 0.f);
  }
  __syncthreads();
  for (int rr = 0; rr < 16; ++rr) {
    int lr = wid * 16 + rr;
    int row = row0 + lr;
    if (row >= N) break;   // uniform per wave
    float a0 = 0.f, a1 = 0.f, a2 = 0.f, a3 = 0.f;
    #pragma unroll
    for (int kk = 0; kk < 16; ++kk) {
      float4 xv = Xs[lr][kk];
      a0 = fmaf(xv.x, wreg[4 * kk + 0], a0);
      a1 = fmaf(xv.y, wreg[4 * kk + 1], a1);
      a2 = fmaf(xv.z, wreg[4 * kk + 2], a2);
      a3 = fmaf(xv.w, wreg[4 * kk + 3], a3);
    }
    float v = fmaxf(a0 + a1 + a2 + a3 + bias, 0.f);
    float y = v * wl;
    #pragma unroll
    for (int off = 32; off > 0; off >>= 1) y += __shfl_down(y, off, 64);
    if (col == 0) yv[lr] = y;
  }
  __syncthreads();
  if (threadIdx.x < 64) {
    int row = row0 + threadIdx.x;
    if (row < N) atomicAdd(&gpart[batch[row]], yv[threadIdx.x]);
  }
  __syncthreads();
  if (threadIdx.x < NUM_GRAPHS) {
    int glo = batch[row0];
    int ghi = batch[min(row0 + 63, N - 1)];
    int g = threadIdx.x;
    if (g >= glo && g <= ghi) atomicAdd(&partial[g], gpart[g]);
  }
}

// ---- finalize: out[g] = partial[g]/count_g + bl ----
__global__ void pool_final_kernel(const float* __restrict__ partial, const int* __restrict__ batch,
                                  const float* __restrict__ bl, float* __restrict__ out, int N) {
  int g = threadIdx.x;  // 64 threads
  int lo = 0, hi = N;
  while (lo < hi) { int m = (lo + hi) >> 1; if (batch[m] < g) lo = m + 1; else hi = m; }
  int start = lo;
  hi = N;
  while (lo < hi) { int m = (lo + hi) >> 1; if (batch[m] < g + 1) lo = m + 1; else hi = m; }
  float c = fmaxf((float)(lo - start), 1.f);
  out[g] = partial[g] / c + bl[0];
}

extern "C" void kernel_launch(void* const* d_in, const int* in_sizes, int n_in,
                              void* d_out, int out_size, void* d_ws, size_t ws_size,
                              hipStream_t stream) {
  const float* x     = (const float*)d_in[0];
  const int*   ei    = (const int*)d_in[1];   // int64 in reference, delivered as int32
  const int*   batch = (const int*)d_in[2];
  const float* W1 = (const float*)d_in[3];
  const float* b1 = (const float*)d_in[4];
  const float* W2 = (const float*)d_in[5];
  const float* b2 = (const float*)d_in[6];
  const float* W3 = (const float*)d_in[7];
  const float* b3 = (const float*)d_in[8];
  const float* Wl = (const float*)d_in[9];
  const float* bl = (const float*)d_in[10];
  float* out = (float*)d_out;

  const int* srcp = ei;
  const int* dstp = ei + N_EDGES;

  char* ws = (char*)d_ws;
  size_t off = 0;
  auto alloc = [&](size_t bytes) { void* p = ws + off; off += (bytes + 255) & ~(size_t)255; return p; };
  int*   cnt     = (int*)  alloc((size_t)N_NODES * 4);        // reused as cursor
  float* dis     = (float*)alloc((size_t)N_NODES * 4);
  int*   rowptr  = (int*)  alloc((size_t)(N_NODES + 1) * 4);
  int*   bsum    = (int*)  alloc(64 * 4);
  float* partial = (float*)alloc(NUM_GRAPHS * 4);
  int*   esrc    = (int*)  alloc((size_t)N_EDGES * 4);
  float* bufA    = (float*)alloc((size_t)N_NODES * DIM * 4);
  float* bufB    = (float*)alloc((size_t)N_NODES * DIM * 4);

  const int NB = (N_NODES + 1023) / 1024;  // 49

  // ---- CSR build ----
  hipMemsetAsync(cnt, 0, (size_t)N_NODES * 4, stream);
  count_deg_kernel<<<(N_EDGES + 255) / 256, 256, 0, stream>>>(dstp, cnt, N_EDGES);
  scanA_kernel<<<NB, 1024, 0, stream>>>(cnt, rowptr, bsum, dis, N_NODES);
  scanB_kernel<<<1, 64, 0, stream>>>(bsum, rowptr, NB, N_NODES);
  scanC_kernel<<<NB, 1024, 0, stream>>>(rowptr, bsum, cnt, N_NODES);
  fill_kernel<<<(N_EDGES + 255) / 256, 256, 0, stream>>>(srcp, dstp, cnt, esrc, N_EDGES);

  // ---- 3 GCN layers ----
  const int GB = (N_NODES + 63) / 64;  // 782
  aggregate_kernel<<<(N_NODES + 3) / 4, 256, 0, stream>>>(x, rowptr, esrc, dis, bufA, N_NODES);
  gemm_bias_relu<<<GB, 256, 0, stream>>>(bufA, W1, b1, bufB, N_NODES);
  aggregate_kernel<<<(N_NODES + 3) / 4, 256, 0, stream>>>(bufB, rowptr, esrc, dis, bufA, N_NODES);
  gemm_bias_relu<<<GB, 256, 0, stream>>>(bufA, W2, b2, bufB, N_NODES);
  aggregate_kernel<<<(N_NODES + 3) / 4, 256, 0, stream>>>(bufB, rowptr, esrc, dis, bufA, N_NODES);
  hipMemsetAsync(partial, 0, NUM_GRAPHS * 4, stream);
  gemm_dot_kernel<<<GB, 256, 0, stream>>>(bufA, W3, b3, Wl, batch, partial, N_NODES);
  pool_final_kernel<<<1, 64, 0, stream>>>(partial, batch, bl, out, N_NODES);
}